// Round 1
// baseline (286.988 us; speedup 1.0000x reference)
//
#include <hip/hip_runtime.h>

// RLSE forward, faithful port. Key structural fact: the reference divides both
// theta and S by GAMMA=1000 every one of the 8192 scan steps, so in fp32 both
// underflow to EXACTLY zero by ~step 20, and (S=0, theta=0) is an exact fixed
// point of the recursion. We run the scan faithfully and stop once the state
// is exactly zero (checked, not assumed); remaining steps are provable no-ops.
// Fallback: if the state never zeroes, the loop runs all `rows` steps (still
// correct, just slow).

#define NN 256          // n_vars + 1
#define PPITCH (NN + 8) // pad to break 4-way LDS bank conflict on partial writes

__global__ __launch_bounds__(1024) void rlse_scan_kernel(
    const float* __restrict__ x, const float* __restrict__ f,
    const float* __restrict__ y, float* __restrict__ theta_out, int rows)
{
    __shared__ float a_sh[NN];
    __shared__ float theta_sh[NN];
    __shared__ float d_sh[NN];
    __shared__ float part[4 * PPITCH];
    __shared__ float red1[4], red2[4];
    __shared__ float s2_sh, e_sh, b_sh;
    __shared__ int flag_sh;

    const int t = threadIdx.x;
    const int row = t >> 2;          // S row owned by this thread
    const int q = t & 3;             // column quarter
    const int colbase = q << 6;      // first column of this thread's 64-col slab
    const bool owns_d = ((row >> 6) == q);  // this slab contains S[row][row]

    // S[row][colbase .. colbase+63] in registers (static indices only!)
    float S[64];
#pragma unroll
    for (int c = 0; c < 64; ++c) S[c] = (colbase + c == row) ? 1.0f : 0.0f;
    // shadow of the diagonal element for the owning thread (avoids dynamic
    // register indexing, which would spill S to scratch)
    float dval = owns_d ? 1.0f : 0.0f;

    if (t < NN) theta_sh[t] = 0.0f;

    for (int k = 0; k < rows; ++k) {
        // ---- Phase A: stage a-row, rhs scalar, diag(S) ----
        if (t < NN) a_sh[t] = x[(size_t)k * NN + t] * f[(size_t)k * NN + t];
        if (owns_d) d_sh[row] = dval;
        if (t == 0) { b_sh = y[k]; flag_sh = 0; }
        __syncthreads();  // B1

        // ---- Phase B: Sa partials (all threads) + s2 / a.theta reductions ----
        float psa = 0.0f;
#pragma unroll
        for (int c = 0; c < 64; ++c) psa += S[c] * a_sh[colbase + c];
        part[q * PPITCH + row] = psa;

        if (t < NN) {
            float av = a_sh[t];
            float p1 = av * av;            // -> s2 = a.a
            float p2 = av * theta_sh[t];   // -> a.theta
#pragma unroll
            for (int off = 32; off > 0; off >>= 1) {
                p1 += __shfl_down(p1, off, 64);
                p2 += __shfl_down(p2, off, 64);
            }
            if ((t & 63) == 0) { red1[t >> 6] = p1; red2[t >> 6] = p2; }
        }
        __syncthreads();  // B2

        if (t == 0) {
            float s2 = red1[0] + red1[1] + red1[2] + red1[3];
            float dt = red2[0] + red2[1] + red2[2] + red2[3];
            s2_sh = s2;
            e_sh = b_sh - dt;              // e = b - a.theta (OLD theta)
        }
        __syncthreads();  // B3

        // ---- Phase C: theta update (old S), then rank-1 S update ----
        const float s2 = s2_sh;
        const float e = e_sh;
        if (t < NN) {
            float sa = part[0 * PPITCH + t] + part[1 * PPITCH + t]
                     + part[2 * PPITCH + t] + part[3 * PPITCH + t];
            theta_sh[t] = (theta_sh[t] + sa * e) / 1000.0f;
        }
        const float drow = d_sh[row];
        const float coef = drow * s2 / (1.0f + drow * s2);  // d_i*s2/x2_i
#pragma unroll
        for (int c = 0; c < 64; ++c)
            S[c] = (S[c] - coef * d_sh[colbase + c]) / 1000.0f;
        dval = (dval - coef * dval) / 1000.0f;  // keep diagonal shadow in sync
        __syncthreads();  // B4

        // ---- Early exit: state exactly zero => fixed point, remaining steps
        //      are provable no-ops ----
        if (((k & 7) == 7) && k >= 23) {
            bool nz = false;
#pragma unroll
            for (int c = 0; c < 64; ++c) nz = nz || (S[c] != 0.0f);
            if (t < NN) nz = nz || (theta_sh[t] != 0.0f);
            if (nz) flag_sh = 1;          // benign race: all writers store 1
            __syncthreads();  // B5
            if (flag_sh == 0) break;      // uniform across the block
        }
    }

    if (t < NN) theta_out[t] = theta_sh[t];
}

// out[r] = dot(x[r, :], theta)  — one wave per row
__global__ __launch_bounds__(256) void rlse_out_kernel(
    const float* __restrict__ x, const float* __restrict__ th,
    float* __restrict__ out, int rows)
{
    const int gid = blockIdx.x * blockDim.x + threadIdx.x;
    const int wave = gid >> 6;
    const int lane = gid & 63;
    if (wave >= rows) return;
    const float* xr = x + (size_t)wave * NN;
    float s = xr[lane]       * th[lane]
            + xr[lane + 64]  * th[lane + 64]
            + xr[lane + 128] * th[lane + 128]
            + xr[lane + 192] * th[lane + 192];
#pragma unroll
    for (int off = 32; off > 0; off >>= 1) s += __shfl_down(s, off, 64);
    if (lane == 0) out[wave] = s;
}

extern "C" void kernel_launch(void* const* d_in, const int* in_sizes, int n_in,
                              void* d_out, int out_size, void* d_ws, size_t ws_size,
                              hipStream_t stream)
{
    const float* x = (const float*)d_in[0];   // (B, R, N) fp32
    const float* f = (const float*)d_in[1];   // (B, R, N) fp32
    const float* y = (const float*)d_in[2];   // (B, R, 1) fp32
    float* out = (float*)d_out;               // (B, R, 1) fp32
    float* theta = (float*)d_ws;              // NN floats of scratch
    const int rows = in_sizes[2];             // B*R sequential scan steps

    rlse_scan_kernel<<<1, 1024, 0, stream>>>(x, f, y, theta, rows);

    const int blocks = (rows * 64 + 255) / 256;  // one wave per output row
    rlse_out_kernel<<<blocks, 256, 0, stream>>>(x, theta, out, rows);
}

// Round 2
// 161.932 us; speedup vs baseline: 1.7723x; 1.7723x over previous
//
#include <hip/hip_runtime.h>

// RLSE forward. The reference divides theta and S by GAMMA=1000 every scan
// step, so in fp32 both underflow to EXACTLY zero by ~step 16 (diag obeys
// d' <= d/1000 strictly), and (S=0, theta=0) is a fixed point. We run the
// scan faithfully and stop once the state is exactly zero (checked, not
// assumed). Exact '/1000' replaced by '*0.001f': reference output is
// exactly 0, and 1-ulp drift cannot prevent the 1e-3/step decay to zero.
//
// launch_bounds(1024,4): 4 waves/EU -> 128 VGPR cap so S[64] stays in real
// VGPRs (bare (1024) capped at 64 VGPR -> S went to AGPRs, accvgpr churn).

#define NN 256          // n_vars + 1
#define PPITCH (NN + 8) // pad partials to break 4-way bank conflicts

__global__ __launch_bounds__(1024, 4) void rlse_scan_kernel(
    const float* __restrict__ x, const float* __restrict__ f,
    const float* __restrict__ y, float* __restrict__ theta_out, int rows)
{
    __shared__ __align__(16) float a_sh[NN];
    __shared__ float theta_sh[NN];
    __shared__ __align__(16) float d_sh[NN];
    __shared__ float part[4 * PPITCH];
    __shared__ float red1[4], red2[4];
    __shared__ int flag_sh;

    const int t = threadIdx.x;
    const int row = t >> 2;                 // S row owned by this thread
    const int q = t & 3;                    // column quarter
    const int colbase = q << 6;             // first column of this 64-col slab
    const bool owns_d = ((row >> 6) == q);  // slab contains S[row][row]

    // S[row][colbase .. colbase+63] in registers (static indices only)
    float S[64];
#pragma unroll
    for (int c = 0; c < 64; ++c) S[c] = (colbase + c == row) ? 1.0f : 0.0f;
    float dval = owns_d ? 1.0f : 0.0f;      // diagonal shadow (no dyn indexing)

    if (t < NN) theta_sh[t] = 0.0f;

    const float4* x4 = (const float4*)x;    // one wave loads a whole 256-row
    const float4* f4 = (const float4*)f;

    float4 rx, rf;
    if (t < 64) { rx = x4[t]; rf = f4[t]; }
    float ry = y[0];                        // uniform -> scalar load

    for (int k = 0; k < rows; ++k) {
        // ---- Phase A: stage a-row (prefetched regs) + diag(S) ----
        if (t < 64) {
            float4 av;
            av.x = rx.x * rf.x; av.y = rx.y * rf.y;
            av.z = rx.z * rf.z; av.w = rx.w * rf.w;
            ((float4*)a_sh)[t] = av;
        }
        if (owns_d) d_sh[row] = dval;
        __syncthreads();  // B1

        // ---- Prefetch next row: latency hides under phases B/C ----
        float ry_next = 0.0f;
        if (k + 1 < rows) {
            if (t < 64) {
                rx = x4[(size_t)(k + 1) * 64 + t];
                rf = f4[(size_t)(k + 1) * 64 + t];
            }
            ry_next = y[k + 1];
        }

        // ---- Phase B: Sa partials (all threads) + s2 / a.theta reductions ----
        const float4* ap = (const float4*)(a_sh + colbase);
        float psa = 0.0f;
#pragma unroll
        for (int i = 0; i < 16; ++i) {
            float4 av = ap[i];
            psa += S[4*i+0]*av.x + S[4*i+1]*av.y + S[4*i+2]*av.z + S[4*i+3]*av.w;
        }
        part[q * PPITCH + row] = psa;

        if (t < NN) {
            float av = a_sh[t];
            float p1 = av * av;              // -> s2 = a.a
            float p2 = av * theta_sh[t];     // -> a.theta (OLD theta)
#pragma unroll
            for (int off = 32; off > 0; off >>= 1) {
                p1 += __shfl_down(p1, off, 64);
                p2 += __shfl_down(p2, off, 64);
            }
            if ((t & 63) == 0) { red1[t >> 6] = p1; red2[t >> 6] = p2; }
        }
        __syncthreads();  // B2

        // ---- Phase C: all threads combine reductions (no t==0 serialization)
        const float s2 = red1[0] + red1[1] + red1[2] + red1[3];
        const float e  = ry - (red2[0] + red2[1] + red2[2] + red2[3]);

        if (t < NN) {
            float sa = part[0 * PPITCH + t] + part[1 * PPITCH + t]
                     + part[2 * PPITCH + t] + part[3 * PPITCH + t];
            theta_sh[t] = (theta_sh[t] + sa * e) * 0.001f;
        }
        if (t == 0) flag_sh = 0;  // reset here (barrier-ordered vs reads below)

        const float drow = d_sh[row];
        const float coef = (drow * s2) * __builtin_amdgcn_rcpf(1.0f + drow * s2);
        const float4* dp = (const float4*)(d_sh + colbase);
#pragma unroll
        for (int i = 0; i < 16; ++i) {
            float4 dv = dp[i];
            S[4*i+0] = (S[4*i+0] - coef * dv.x) * 0.001f;
            S[4*i+1] = (S[4*i+1] - coef * dv.y) * 0.001f;
            S[4*i+2] = (S[4*i+2] - coef * dv.z) * 0.001f;
            S[4*i+3] = (S[4*i+3] - coef * dv.w) * 0.001f;
        }
        dval = (dval - coef * dval) * 0.001f;
        __syncthreads();  // B4
        ry = ry_next;

        // ---- Early exit: state exactly zero => fixed point ----
        if (k >= 13) {
            bool nz = (dval != 0.0f);
#pragma unroll
            for (int c = 0; c < 64; ++c) nz = nz || (S[c] != 0.0f);
            if (t < NN) nz = nz || (theta_sh[t] != 0.0f);
            if (nz) flag_sh = 1;
            __syncthreads();  // B5
            if (flag_sh == 0) break;  // uniform; flag reset is after next B2
        }
    }

    if (t < NN) theta_out[t] = theta_sh[t];
}

// out[r] = dot(x[r, :], theta) — one wave per row, float4 loads
__global__ __launch_bounds__(256) void rlse_out_kernel(
    const float* __restrict__ x, const float* __restrict__ th,
    float* __restrict__ out, int rows)
{
    const int gid = blockIdx.x * blockDim.x + threadIdx.x;
    const int wave = gid >> 6;
    const int lane = gid & 63;
    if (wave >= rows) return;
    const float4 xv = ((const float4*)(x + (size_t)wave * NN))[lane];
    const float4 tv = ((const float4*)th)[lane];
    float s = xv.x * tv.x + xv.y * tv.y + xv.z * tv.z + xv.w * tv.w;
#pragma unroll
    for (int off = 32; off > 0; off >>= 1) s += __shfl_down(s, off, 64);
    if (lane == 0) out[wave] = s;
}

extern "C" void kernel_launch(void* const* d_in, const int* in_sizes, int n_in,
                              void* d_out, int out_size, void* d_ws, size_t ws_size,
                              hipStream_t stream)
{
    const float* x = (const float*)d_in[0];   // (B, R, N) fp32
    const float* f = (const float*)d_in[1];   // (B, R, N) fp32
    const float* y = (const float*)d_in[2];   // (B, R, 1) fp32
    float* out = (float*)d_out;               // (B, R, 1) fp32
    float* theta = (float*)d_ws;              // NN floats scratch
    const int rows = in_sizes[2];             // B*R sequential steps

    rlse_scan_kernel<<<1, 1024, 0, stream>>>(x, f, y, theta, rows);

    const int blocks = (rows * 64 + 255) / 256;  // one wave per output row
    rlse_out_kernel<<<blocks, 256, 0, stream>>>(x, theta, out, rows);
}

// Round 3
// 72.167 us; speedup vs baseline: 3.9767x; 2.2438x over previous
//
#include <hip/hip_runtime.h>

// RLSE forward — collapsed-state formulation.
//
// Structural fact #1: in the reference's own fp arithmetic, S always has
// exactly TWO distinct values. S0 = I; the update
//   S_new[i,j] = (S[i,j] - d_i*d_j*s2/x2_i)/gamma,  x2_i = 1 + d_i*s2
// applies a bit-identical op to every diagonal entry (d uniform by induction,
// s2 scalar) and to every off-diagonal entry. So S = ov*1*1^T + (dv-ov)*I,
// and S@a = dv*a + ov*(suma - a). The 256x256 scan state collapses to
// {dv, ov, theta[256]} -> single wave, no barriers, no LDS.
//
// Structural fact #2: gamma=1000 divides dv, ov, theta every step, so all
// underflow to EXACTLY 0 by step ~17; (dv=0, ov=0, theta=0) is an exact
// fixed point (z = 0*a + 0*(...) = 0, theta' = (0+0*e)*1e-3 = 0). We scan
// faithfully and exit once the state is exactly zero (checked via ballot,
// not assumed). Fallback: loop runs all `rows` steps if it never zeroes.

#define NN 256  // n_vars + 1

__global__ __launch_bounds__(64) void rlse_scan_kernel(
    const float* __restrict__ x, const float* __restrict__ f,
    const float* __restrict__ y, float* __restrict__ theta_out, int rows)
{
    const int l = threadIdx.x;  // lane 0..63, owns elements 4l..4l+3
    const float4* x4 = (const float4*)x;
    const float4* f4 = (const float4*)f;

    float th0 = 0.0f, th1 = 0.0f, th2 = 0.0f, th3 = 0.0f;  // theta[4l..4l+3]
    float dv = 1.0f;  // S diagonal value (uniform)
    float ov = 0.0f;  // S off-diagonal value (uniform)

    float4 rx = x4[l], rf = f4[l];  // prefetched current row
    float ry = y[0];

    for (int k = 0; k < rows; ++k) {
        // a = x*f for this row (per-lane 4 elements)
        const float a0 = rx.x * rf.x, a1 = rx.y * rf.y;
        const float a2 = rx.z * rf.z, a3 = rx.w * rf.w;

        // prefetch next row — HBM latency hides under the reductions
        float4 nx = rx, nf = rf; float ny = 0.0f;
        if (k + 1 < rows) {
            nx = x4[(size_t)(k + 1) * 64 + l];
            nf = f4[(size_t)(k + 1) * 64 + l];
            ny = y[k + 1];
        }

        // three batched butterfly reductions: suma, s2=a.a, ta=a.theta
        float ps = a0 + a1 + a2 + a3;
        float p2 = a0 * a0 + a1 * a1 + a2 * a2 + a3 * a3;
        float pt = a0 * th0 + a1 * th1 + a2 * th2 + a3 * th3;
#pragma unroll
        for (int off = 32; off > 0; off >>= 1) {
            ps += __shfl_xor(ps, off, 64);
            p2 += __shfl_xor(p2, off, 64);
            pt += __shfl_xor(pt, off, 64);
        }
        const float suma = ps, s2 = p2;
        const float e = ry - pt;                 // e = b - a.theta (OLD theta)

        // scalar S-state update ingredients (uniform across lanes)
        const float x2 = 1.0f + dv * s2;
        const float c  = (dv * dv) * s2 / x2;    // d_i*d_j*s2/x2 (all entries)

        // z = S@a = dv*a + ov*(suma - a); theta' = (theta + z*e)*1e-3
        const float z0 = dv * a0 + ov * (suma - a0);
        const float z1 = dv * a1 + ov * (suma - a1);
        const float z2 = dv * a2 + ov * (suma - a2);
        const float z3 = dv * a3 + ov * (suma - a3);
        th0 = (th0 + z0 * e) * 0.001f;
        th1 = (th1 + z1 * e) * 0.001f;
        th2 = (th2 + z2 * e) * 0.001f;
        th3 = (th3 + z3 * e) * 0.001f;

        dv = (dv - c) * 0.001f;
        ov = (ov - c) * 0.001f;

        rx = nx; rf = nf; ry = ny;

        // early exit: state exactly zero => provable fixed point
        if (k >= 13) {
            const bool nz = (dv != 0.0f) | (ov != 0.0f) |
                            (th0 != 0.0f) | (th1 != 0.0f) |
                            (th2 != 0.0f) | (th3 != 0.0f);
            if (__ballot(nz) == 0ULL) break;  // wave-uniform, no barrier
        }
    }

    float4 t4; t4.x = th0; t4.y = th1; t4.z = th2; t4.w = th3;
    ((float4*)theta_out)[l] = t4;  // 64 lanes x 4 = all 256 elements
}

// out[r] = dot(x[r, :], theta) — one wave per row, float4 loads
__global__ __launch_bounds__(256) void rlse_out_kernel(
    const float* __restrict__ x, const float* __restrict__ th,
    float* __restrict__ out, int rows)
{
    const int gid = blockIdx.x * blockDim.x + threadIdx.x;
    const int wave = gid >> 6;
    const int lane = gid & 63;
    if (wave >= rows) return;
    const float4 xv = ((const float4*)(x + (size_t)wave * NN))[lane];
    const float4 tv = ((const float4*)th)[lane];
    float s = xv.x * tv.x + xv.y * tv.y + xv.z * tv.z + xv.w * tv.w;
#pragma unroll
    for (int off = 32; off > 0; off >>= 1) s += __shfl_down(s, off, 64);
    if (lane == 0) out[wave] = s;
}

extern "C" void kernel_launch(void* const* d_in, const int* in_sizes, int n_in,
                              void* d_out, int out_size, void* d_ws, size_t ws_size,
                              hipStream_t stream)
{
    const float* x = (const float*)d_in[0];   // (B, R, N) fp32
    const float* f = (const float*)d_in[1];   // (B, R, N) fp32
    const float* y = (const float*)d_in[2];   // (B, R, 1) fp32
    float* out = (float*)d_out;               // (B, R, 1) fp32
    float* theta = (float*)d_ws;              // NN floats scratch
    const int rows = in_sizes[2];             // B*R sequential steps

    rlse_scan_kernel<<<1, 64, 0, stream>>>(x, f, y, theta, rows);

    const int blocks = (rows * 64 + 255) / 256;  // one wave per output row
    rlse_out_kernel<<<blocks, 256, 0, stream>>>(x, theta, out, rows);
}